// Round 4
// baseline (1652.740 us; speedup 1.0000x reference)
//
#include <hip/hip_runtime.h>

// Dims from reference: X=1, Z=16, H=16, G=8, I=16, T=512, B=2048
#define T_LEN 512
#define BATCH 2048
#define OUTW  66   // [mu_x(1), logvar_x(1), mu_z(16), logvar_z(16), mu_tr(16), logvar_tr(16)]

typedef unsigned short u16;
typedef unsigned int   u32;

__device__ __forceinline__ float bf2f(u16 u) {
    union { u32 i; float f; } v; v.i = ((u32)u) << 16; return v.f;
}
__device__ __forceinline__ u16 f2bf(float f) {
    union { u32 i; float f; } v; v.f = f;
    u32 x = v.i;
    return (u16)((x + 0x7fffu + ((x >> 16) & 1u)) >> 16);  // RNE
}
__device__ __forceinline__ float fexp2(float x) { return __builtin_amdgcn_exp2f(x); }
__device__ __forceinline__ float frcp(float x)  { return __builtin_amdgcn_rcpf(x); }
// tanh(x) = 2/(1+exp2(-2*log2e*x)) - 1 ; saturates correctly at +-1
__device__ __forceinline__ float ftanh(float x) {
    return fmaf(2.f, frcp(1.f + fexp2(-2.88539008f * x)), -1.f);
}

// Input accessor: inputs are float32 per the reference (proven by rounds 2->3:
// bf16 interpretation gave NaN, f32 gives finite). Keep runtime detection as a
// guard; `f32` is wave-uniform.
__device__ __forceinline__ float ldin(const void* p, int i, bool f32) {
    return f32 ? ((const float*)p)[i] : bf2f(((const u16*)p)[i]);
}

// Detect input dtype from lstm_Whh's bit pattern (1024 elems, |v| <= 0.25).
// bf16-truth: every u16 exponent field <= 125. f32-truth: the 512 low-mantissa
// u16 halves have ~uniform "exponent" bits -> some exceed 125 w.p. ~1.
__device__ __forceinline__ bool detect_f32(const void* whh) {
    const u16* w = (const u16*)whh;
    int bad = 0;
    for (int i = (threadIdx.x & 63); i < 1024; i += 64) {
        int e = (w[i] >> 7) & 0xFF;
        bad |= (e > 125) ? 1 : 0;
    }
    return __any(bad) != 0;
}

// ---------------------------------------------------------------------------
// K1: one wave per batch element. ZERO global workspace.
// Phase 1: backward LSTM (t=T-1..0). Lane l owns gate l (i:0-15,f:16-31,
//          g:32-47,o:48-63); h,c live on lanes 0..15. h_seq -> LDS (bf16, 16KB).
// Phase 2: forward DKF scan (t=0..T-1), z state on lanes 16..31.
//          Writes mu_z/logvar_z to out ch 2..33 (f32), stashes z_prev -> ch
//          34..49 and z_t -> ch 50..65 (f32; K3 consumes & overwrites).
// ---------------------------------------------------------------------------
__global__ __launch_bounds__(64, 2)
void dkf_scan_kernel(const void* __restrict__ x,
                     const void* __restrict__ eps_z,
                     const void* __restrict__ Wih,  const void* __restrict__ Whh,
                     const void* __restrict__ bih,  const void* __restrict__ bhh,
                     const void* __restrict__ cW1,  const void* __restrict__ cb1,
                     const void* __restrict__ cW2,  const void* __restrict__ cb2,
                     const void* __restrict__ eW1,  const void* __restrict__ eb1,
                     const void* __restrict__ eW2,  const void* __restrict__ eb2,
                     float* __restrict__ out)
{
    __shared__ u16 hbuf[T_LEN * 16];   // 16 KiB: h_seq for this batch element

    const bool F32 = detect_f32(Whh);
    const int b    = blockIdx.x;
    const int lane = threadIdx.x;   // 0..63

    // ---------------- Phase 1: backward LSTM ----------------
    const float wih_l  = ldin(Wih, lane, F32);                     // X_DIM == 1
    const float bias_l = ldin(bih, lane, F32) + ldin(bhh, lane, F32);
    float wh[16];
#pragma unroll
    for (int k = 0; k < 16; ++k) wh[k] = ldin(Whh, lane * 16 + k, F32);

    const bool  is_g    = (lane >= 32) && (lane < 48);
    const float nlscale = is_g ? -2.88539008f : -1.44269504f; // -log2(e)*scale
    const float scale   = is_g ? 2.f : 1.f;
    const float off     = is_g ? 1.f : 0.f;

    float h = 0.f, c = 0.f;
    for (int t = T_LEN - 1; t >= 0; --t) {
        const float xt = ldin(x, t * BATCH + b, F32);
        float a0 = fmaf(wih_l, xt, bias_l);
        float a1 = 0.f, a2 = 0.f, a3 = 0.f;
#pragma unroll
        for (int k = 0; k < 16; k += 4) {
            a0 = fmaf(wh[k],     __shfl(h, k,     64), a0);
            a1 = fmaf(wh[k + 1], __shfl(h, k + 1, 64), a1);
            a2 = fmaf(wh[k + 2], __shfl(h, k + 2, 64), a2);
            a3 = fmaf(wh[k + 3], __shfl(h, k + 3, 64), a3);
        }
        const float gate = (a0 + a1) + (a2 + a3);
        // sigmoid for i/f/o lanes, tanh for g lanes (scale trick)
        const float sg = frcp(1.f + fexp2(nlscale * gate));
        const float a  = fmaf(scale, sg, -off);
        // gather f/g/o activations onto lanes 0..15
        const float af = __shfl(a, (lane + 16) & 63, 64);
        const float ag = __shfl(a, (lane + 32) & 63, 64);
        const float ao = __shfl(a, (lane + 48) & 63, 64);
        c = fmaf(af, c, a * ag);       // lanes 0..15: sig(f)*c + sig(i)*tanh(g)
        h = ao * ftanh(c);             // lanes 0..15: sig(o)*tanh(c)
        if (lane < 16) hbuf[t * 16 + lane] = f2bf(h);
    }

    __syncthreads();

    // ---------------- Phase 2: forward DKF scan ----------------
    // comb_W1 halves: lanes 0..15 take h-columns, lanes 16..31 take z-columns
    float w1[16];
    {
        const int r    = lane & 15;
        const int base = (lane < 16) ? (r * 32) : (r * 32 + 16);
#pragma unroll
        for (int k = 0; k < 16; ++k) w1[k] = ldin(cW1, base + k, F32);
    }
    const float cb1_l = ldin(cb1, lane & 15, F32);
    float w2[16];
#pragma unroll
    for (int k = 0; k < 16; ++k) w2[k] = ldin(cW2, (lane & 7) * 16 + k, F32);
    const float cb2_l = ldin(cb2, lane & 7, F32);
    float we1[8];
#pragma unroll
    for (int k = 0; k < 8; ++k) we1[k] = ldin(eW1, (lane & 15) * 8 + k, F32);
    const float eb1_l = ldin(eb1, lane & 15, F32);
    float we2[16];
#pragma unroll
    for (int k = 0; k < 16; ++k) we2[k] = ldin(eW2, (lane & 31) * 16 + k, F32);
    const float eb2_l = ldin(eb2, lane & 31, F32);

    float zst = 0.f;                    // lanes 16..31 hold z_prev[lane-16]; z0 = 0
    const int srcbase = lane & 16;

    for (int t = 0; t < T_LEN; ++t) {
        const int tb = t * BATCH + b;
        const size_t rowbase = (size_t)tb * OUTW;
        // s: lanes 0..15 = h_t (from LDS), lanes 16..31 = z_prev
        const float sreg = (lane < 16) ? bf2f(hbuf[t * 16 + lane]) : zst;

        // comb layer 1: 16 outs over 32 ins, split across lane halves
        float p0 = 0.f, p1 = 0.f, p2 = 0.f, p3 = 0.f;
#pragma unroll
        for (int k = 0; k < 16; k += 4) {
            p0 = fmaf(w1[k],     __shfl(sreg, srcbase + k,     64), p0);
            p1 = fmaf(w1[k + 1], __shfl(sreg, srcbase + k + 1, 64), p1);
            p2 = fmaf(w1[k + 2], __shfl(sreg, srcbase + k + 2, 64), p2);
            p3 = fmaf(w1[k + 3], __shfl(sreg, srcbase + k + 3, 64), p3);
        }
        const float part = (p0 + p1) + (p2 + p3);
        const float a1v  = ftanh(part + __shfl(part, (lane + 16) & 63, 64) + cb1_l); // lanes 0..15

        // comb layer 2: 8 outs over 16 ins (lanes 0..7)
        float q0 = cb2_l, q1 = 0.f, q2 = 0.f, q3 = 0.f;
#pragma unroll
        for (int k = 0; k < 16; k += 4) {
            q0 = fmaf(w2[k],     __shfl(a1v, k,     64), q0);
            q1 = fmaf(w2[k + 1], __shfl(a1v, k + 1, 64), q1);
            q2 = fmaf(w2[k + 2], __shfl(a1v, k + 2, 64), q2);
            q3 = fmaf(w2[k + 3], __shfl(a1v, k + 3, 64), q3);
        }
        const float g = (q0 + q1) + (q2 + q3);   // lanes 0..7

        // enc layer 1: 16 outs over 8 ins (lanes 0..15)
        float r0 = eb1_l, r1 = 0.f;
#pragma unroll
        for (int k = 0; k < 8; k += 2) {
            r0 = fmaf(we1[k],     __shfl(g, k,     64), r0);
            r1 = fmaf(we1[k + 1], __shfl(g, k + 1, 64), r1);
        }
        const float e1 = ftanh(r0 + r1);         // lanes 0..15

        // enc layer 2: 32 outs over 16 ins (lanes 0..31): mu on 0..15, logvar on 16..31
        float s0 = eb2_l, s1 = 0.f, s2 = 0.f, s3 = 0.f;
#pragma unroll
        for (int k = 0; k < 16; k += 4) {
            s0 = fmaf(we2[k],     __shfl(e1, k,     64), s0);
            s1 = fmaf(we2[k + 1], __shfl(e1, k + 1, 64), s1);
            s2 = fmaf(we2[k + 2], __shfl(e1, k + 2, 64), s2);
            s3 = fmaf(we2[k + 3], __shfl(e1, k + 3, 64), s3);
        }
        const float e2 = (s0 + s1) + (s2 + s3);

        // reparameterize: z = mu + eps * exp(0.5*logvar) on lanes 0..15
        const float lv  = fminf(__shfl(e2, (lane + 16) & 63, 64), 40.f);
        const float eps = ldin(eps_z, tb * 16 + (lane & 15), F32);
        const float zn  = fmaf(eps, fexp2(0.72134752f * lv), e2);

        if (lane < 32) out[rowbase + 2 + lane] = e2;                     // mu_z | logvar_z
        if (lane >= 16 && lane < 32) out[rowbase + 34 + (lane - 16)] = zst; // z_prev stash
        if (lane < 16) out[rowbase + 50 + lane] = zn;                    // z_t stash
        zst = __shfl(zn, lane & 15, 64);   // lanes 16..31 pick up new z
    }
}

// ---------------------------------------------------------------------------
// K3: dec + tr heads, fully parallel over T*B. Weights staged in LDS.
// Reads z_t / z_prev (f32) from its OWN row's stash channels, overwrites them.
// ---------------------------------------------------------------------------
__global__ __launch_bounds__(256)
void dkf_dectr_kernel(const void* __restrict__ Whh,   // for dtype detection only
                      const void* __restrict__ dW1, const void* __restrict__ db1,
                      const void* __restrict__ dW2, const void* __restrict__ db2,
                      const void* __restrict__ tW1, const void* __restrict__ tb1,
                      const void* __restrict__ tW2, const void* __restrict__ tb2,
                      float* __restrict__ out)
{
    __shared__ float sdW1[256], sdb1[16], sdW2[32], sdb2[2];
    __shared__ float stW1[256], stb1[16], stW2[512], stb2[32];
    const bool F32 = detect_f32(Whh);
    const int tid = threadIdx.x;

    { // cooperative weight load -> f32 LDS
        sdW1[tid] = ldin(dW1, tid, F32);
        stW1[tid] = ldin(tW1, tid, F32);
        stW2[tid]       = ldin(tW2, tid, F32);
        stW2[tid + 256] = ldin(tW2, tid + 256, F32);
        if (tid < 16) { sdb1[tid] = ldin(db1, tid, F32); stb1[tid] = ldin(tb1, tid, F32); }
        if (tid < 32) { sdW2[tid] = ldin(dW2, tid, F32); stb2[tid] = ldin(tb2, tid, F32); }
        if (tid < 2)  { sdb2[tid] = ldin(db2, tid, F32); }
    }
    __syncthreads();

    const int idx = blockIdx.x * 256 + tid;          // idx = t*BATCH + b, grid exact
    float* o = out + (size_t)idx * OUTW;

    float z[16], zp[16];
#pragma unroll
    for (int j = 0; j < 16; ++j) z[j]  = o[50 + j];
#pragma unroll
    for (int j = 0; j < 16; ++j) zp[j] = o[34 + j];

    // dec: a = tanh(z @ dW1^T + db1); [mu_x, logvar_x] = a @ dW2^T + db2
    float a[16];
#pragma unroll
    for (int r = 0; r < 16; ++r) {
        float acc = sdb1[r];
#pragma unroll
        for (int k = 0; k < 16; ++k) acc = fmaf(sdW1[r * 16 + k], z[k], acc);
        a[r] = ftanh(acc);
    }
    float mux = sdb2[0], lvx = sdb2[1];
#pragma unroll
    for (int k = 0; k < 16; ++k) {
        mux = fmaf(sdW2[k],      a[k], mux);
        lvx = fmaf(sdW2[16 + k], a[k], lvx);
    }

    // tr: at = tanh(z_prev @ tW1^T + tb1); [mu_tr, logvar_tr] = at @ tW2^T + tb2
    float at[16];
#pragma unroll
    for (int r = 0; r < 16; ++r) {
        float acc = stb1[r];
#pragma unroll
        for (int k = 0; k < 16; ++k) acc = fmaf(stW1[r * 16 + k], zp[k], acc);
        at[r] = ftanh(acc);
    }

    o[0] = mux;
    o[1] = lvx;
#pragma unroll
    for (int r = 0; r < 32; ++r) {
        float acc = stb2[r];
#pragma unroll
        for (int k = 0; k < 16; ++k) acc = fmaf(stW2[r * 16 + k], at[k], acc);
        o[34 + r] = acc;   // mu_tr | logvar_tr overwrite the stash
    }
}

extern "C" void kernel_launch(void* const* d_in, const int* in_sizes, int n_in,
                              void* d_out, int out_size, void* d_ws, size_t ws_size,
                              hipStream_t stream) {
    (void)in_sizes; (void)n_in; (void)out_size; (void)d_ws; (void)ws_size;
    const void* x       = d_in[0];
    const void* eps_z   = d_in[1];
    const void* Wih     = d_in[2];
    const void* Whh     = d_in[3];
    const void* bih     = d_in[4];
    const void* bhh     = d_in[5];
    const void* cW1     = d_in[6];
    const void* cb1     = d_in[7];
    const void* cW2     = d_in[8];
    const void* cb2     = d_in[9];
    const void* eW1     = d_in[10];
    const void* eb1     = d_in[11];
    const void* eW2     = d_in[12];
    const void* eb2     = d_in[13];
    const void* dW1     = d_in[14];
    const void* db1     = d_in[15];
    const void* dW2     = d_in[16];
    const void* db2     = d_in[17];
    const void* tW1     = d_in[18];
    const void* tb1     = d_in[19];
    const void* tW2     = d_in[20];
    const void* tb2     = d_in[21];

    float* out = (float*)d_out;

    dkf_scan_kernel<<<BATCH, 64, 0, stream>>>(
        x, eps_z, Wih, Whh, bih, bhh,
        cW1, cb1, cW2, cb2, eW1, eb1, eW2, eb2,
        out);

    dkf_dectr_kernel<<<(T_LEN * BATCH) / 256, 256, 0, stream>>>(
        Whh, dW1, db1, dW2, db2, tW1, tb1, tW2, tb2, out);
}